// Round 7
// baseline (1098.726 us; speedup 1.0000x reference)
//
#include <hip/hip_runtime.h>
#include <hip/hip_bf16.h>
#include <hip/hip_cooperative_groups.h>

#define N_NODES 50000
#define N_EDGES 1000000
#define C       128
#define N_REL   8
#define N_SEG   (N_NODES * N_REL)       // 400000
#define KTOT    (N_REL * C + C)         // 1152 = 8 rel chunks + self
#define KC_CNT  (KTOT / 32)             // 36 MFMA k-chunks
#define A_STRIDE 1160                   // 1152 + 8 bf16 pad per row
#define NCHUNK  ((N_SEG + 1023) / 1024) // 391 scan chunks

typedef __hip_bfloat16  bf16;
typedef __hip_bfloat162 bf162;
typedef __attribute__((ext_vector_type(8))) short short8;
typedef __attribute__((ext_vector_type(4))) float f32x4;

// ---------------------------------------------------------------- weight fragment index
// B-fragment for mfma_f32_16x16x32_bf16: lane = quad*16 + (n&15) holds
// B[k = kc*32 + quad*8 + j][n], j=0..7 contiguous.
__device__ __forceinline__ size_t frag_index(int k, int n) {
    int nt = n >> 4, n15 = n & 15;
    int kc = k >> 5, quad = (k >> 3) & 3, j = k & 7;
    int lane = quad * 16 + n15;
    return ((size_t)(nt * KC_CNT + kc) * 64 + lane) * 8 + j;
}

// ---------------------------------------------------------------- cooperative mega-prep
// One dispatch: zero+cvt | count | scan(3 sub-phases) | fill | CSR-move + weight repack.
struct MegaP {
    const float2* xf; unsigned int* xb;
    const int* src; const int* dst; const int* et;
    int* cnt;                  // [N_SEG] counts, then fill cursor
    int* offs; int* partials; int* pofs; int* srcs_t;   // scratch CSR (d_out)
    int* offs2; int* srcs2;                             // final CSR (ei buffer)
    const float* W1; const float* root1;
    const float* W2; const float* root2; const float* linW;
    const float* b2; const float* linb;
    bf16* Bp1; bf16* Bp2; float* b2p;                   // packed weights (et buffer)
};

__global__ __launch_bounds__(256) void mega_prep(MegaP p) {
    cooperative_groups::grid_group grid = cooperative_groups::this_grid();
    const int gs = gridDim.x * blockDim.x;
    const int gt = blockIdx.x * blockDim.x + threadIdx.x;
    const int t  = threadIdx.x;
    __shared__ int tot[256];

    // ---- phase 1: zero counts + convert x -> bf16 pairs
    for (int i = gt; i < N_SEG; i += gs) p.cnt[i] = 0;
    for (int i = gt; i < N_NODES * C / 2; i += gs) {
        float2 v = p.xf[i];
        union { bf162 h; unsigned int u; } cv;
        cv.h = bf162(__float2bfloat16(v.x), __float2bfloat16(v.y));
        p.xb[i] = cv.u;
    }
    grid.sync();

    // ---- phase 2: per-segment edge counts
    for (int e = gt; e < N_EDGES; e += gs)
        atomicAdd(&p.cnt[p.dst[e] * N_REL + p.et[e]], 1);
    grid.sync();

    // ---- phase 3a: per-chunk exclusive scan (1024 elems/chunk)
    for (int c = blockIdx.x; c < NCHUNK; c += gridDim.x) {
        int base = c * 1024 + t * 4;
        int v0 = (base + 0 < N_SEG) ? p.cnt[base + 0] : 0;
        int v1 = (base + 1 < N_SEG) ? p.cnt[base + 1] : 0;
        int v2 = (base + 2 < N_SEG) ? p.cnt[base + 2] : 0;
        int v3 = (base + 3 < N_SEG) ? p.cnt[base + 3] : 0;
        int tsum = v0 + v1 + v2 + v3;
        tot[t] = tsum;
        __syncthreads();
        for (int d = 1; d < 256; d <<= 1) {
            int x = tot[t];
            int y = (t >= d) ? tot[t - d] : 0;
            __syncthreads();
            tot[t] = x + y;
            __syncthreads();
        }
        int excl = tot[t] - tsum;
        if (base + 0 < N_SEG) p.offs[base + 0] = excl;
        if (base + 1 < N_SEG) p.offs[base + 1] = excl + v0;
        if (base + 2 < N_SEG) p.offs[base + 2] = excl + v0 + v1;
        if (base + 3 < N_SEG) p.offs[base + 3] = excl + v0 + v1 + v2;
        if (t == 255) p.partials[c] = tot[255];
        __syncthreads();
    }
    grid.sync();

    // ---- phase 3b: block 0 scans the 391 chunk partials (2 per thread)
    if (blockIdx.x == 0) {
        int a = (2 * t     < NCHUNK) ? p.partials[2 * t]     : 0;
        int b = (2 * t + 1 < NCHUNK) ? p.partials[2 * t + 1] : 0;
        int psum = a + b;
        tot[t] = psum;
        __syncthreads();
        for (int d = 1; d < 256; d <<= 1) {
            int x = tot[t];
            int y = (t >= d) ? tot[t - d] : 0;
            __syncthreads();
            tot[t] = x + y;
            __syncthreads();
        }
        int excl = tot[t] - psum;
        if (2 * t     < NCHUNK) p.pofs[2 * t]     = excl;
        if (2 * t + 1 < NCHUNK) p.pofs[2 * t + 1] = excl + a;
    }
    grid.sync();

    // ---- phase 3c: add chunk bases; init fill cursor; sentinel
    for (int c = blockIdx.x; c < NCHUNK; c += gridDim.x) {
        int add = p.pofs[c];
        int base = c * 1024 + t * 4;
#pragma unroll
        for (int j = 0; j < 4; j++)
            if (base + j < N_SEG) {
                int v = p.offs[base + j] + add;
                p.offs[base + j] = v;
                p.cnt[base + j]  = v;
            }
    }
    if (gt == 0) p.offs[N_SEG] = N_EDGES;
    grid.sync();

    // ---- phase 4: fill (atomic ticket)
    for (int e = gt; e < N_EDGES; e += gs) {
        int seg = p.dst[e] * N_REL + p.et[e];
        int pos = atomicAdd(&p.cnt[seg], 1);
        p.srcs_t[pos] = p.src[e];
    }
    grid.sync();

    // ---- phase 5: relocate CSR into ei buffer (ei dead now) + repack weights (et dead now)
    for (int i = gt; i < N_SEG + 1; i += gs) p.offs2[i] = p.offs[i];
    for (int i = gt; i < N_EDGES; i += gs)  p.srcs2[i] = p.srcs_t[i];
    for (int idx = gt; idx < KTOT * C; idx += gs) {
        int k = idx >> 7, n = idx & 127;
        float val;
        if (k < N_REL * C) val = p.W1[(size_t)k * C + n];
        else               val = p.root1[(size_t)(k - N_REL * C) * C + n];
        p.Bp1[frag_index(k, n)] = __float2bfloat16(val);
    }
    for (int idx = gt; idx < KTOT * C; idx += gs) {
        int k = idx >> 7, n = idx & 127;
        const float* row = (k < N_REL * C) ? (p.W2 + (size_t)k * C)
                                           : (p.root2 + (size_t)(k - N_REL * C) * C);
        float acc = 0.f;
        for (int m = 0; m < C; m++)
            acc += row[m] * p.linW[(size_t)m * C + n];
        p.Bp2[frag_index(k, n)] = __float2bfloat16(acc);
    }
    for (int n = gt; n < C; n += gs) {
        float acc = p.linb[n];
        for (int m = 0; m < C; m++)
            acc += p.b2[m] * p.linW[(size_t)m * C + n];
        p.b2p[n] = acc;
    }
}

// ---------------------------------------------------------------- fused layer
// Block: 16 nodes, 256 threads (4 waves). Wave w owns local segments
// [32w, 32w+32) (contiguous CSR edge range). Edges in unconditional 16-deep
// batches so 16 srcs loads + 16 feature gathers stay in flight.
template <int RELU, int OUT_F32>
__global__ __launch_bounds__(256, 4) void fused_layer(
        const unsigned int* __restrict__ featu,  // [N][64] bf16 pairs
        const int*   __restrict__ offs,          // [N_SEG+1]
        const int*   __restrict__ srcs,          // [N_EDGES]
        const short8* __restrict__ Bp,           // fragment-packed bf16 weights
        const float* __restrict__ bias,          // [128] fp32
        void* __restrict__ outp)                 // [N][128] fp32 or bf16
{
    __shared__ __align__(16) unsigned int At[16 * (A_STRIDE / 2)];  // bf16 pairs
    __shared__ int offsL[129];
    const int tid  = threadIdx.x;
    const int lane = tid & 63;
    const int w    = tid >> 6;
    const int v0   = blockIdx.x * 16;

    if (tid < 129) offsL[tid] = offs[v0 * 8 + tid];
    if (tid < 64)  At[(tid >> 2) * (A_STRIDE / 2) + 576 + (tid & 3)] = 0u;  // pad pairs

    // self rows -> k range [1024..1151]
    for (int q = tid; q < 16 * 64; q += 256) {
        int node = q >> 6, pch = q & 63;
        At[node * (A_STRIDE / 2) + 512 + pch] = featu[(size_t)(v0 + node) * 64 + pch];
    }
    __syncthreads();

    // ---- aggregation over wave-owned contiguous edge range
    {
        const int segLo = w * 32;
        const int segHi = segLo + 32;
        int curSeg = segLo;
        int segEnd = offsL[curSeg + 1];
        int i      = offsL[segLo];
        const int eend = offsL[segHi];
        float a0 = 0.f, a1 = 0.f;

        // fast path: full 16-edge batches, unconditional loads
        while (i + 16 <= eend) {
            int sv[16];
#pragma unroll
            for (int j = 0; j < 16; j++) sv[j] = srcs[i + j];
            unsigned int vals[16];
#pragma unroll
            for (int j = 0; j < 16; j++) vals[j] = featu[(size_t)sv[j] * 64 + lane];
#pragma unroll
            for (int j = 0; j < 16; j++) {
                while (i + j == segEnd) {           // flush finished segment(s)
                    int b = offsL[curSeg];
                    float inv = (segEnd > b) ? 1.0f / (float)(segEnd - b) : 0.0f;
                    union { bf162 h; unsigned int u; } cv;
                    cv.h = bf162(__float2bfloat16(a0 * inv), __float2bfloat16(a1 * inv));
                    At[(curSeg >> 3) * (A_STRIDE / 2) + (curSeg & 7) * 64 + lane] = cv.u;
                    a0 = 0.f; a1 = 0.f;
                    curSeg++;
                    segEnd = offsL[curSeg + 1];
                }
                union { bf162 h; unsigned int u; } uv; uv.u = vals[j];
                a0 += __low2float(uv.h);
                a1 += __high2float(uv.h);
            }
            i += 16;
        }
        // predicated tail batch (m < 16, wave-uniform)
        {
            int m = eend - i;
            int sv[16];
#pragma unroll
            for (int j = 0; j < 16; j++) if (j < m) sv[j] = srcs[i + j];
            unsigned int vals[16];
#pragma unroll
            for (int j = 0; j < 16; j++) if (j < m) vals[j] = featu[(size_t)sv[j] * 64 + lane];
#pragma unroll
            for (int j = 0; j < 16; j++) {
                if (j < m) {
                    while (i + j == segEnd) {
                        int b = offsL[curSeg];
                        float inv = (segEnd > b) ? 1.0f / (float)(segEnd - b) : 0.0f;
                        union { bf162 h; unsigned int u; } cv;
                        cv.h = bf162(__float2bfloat16(a0 * inv), __float2bfloat16(a1 * inv));
                        At[(curSeg >> 3) * (A_STRIDE / 2) + (curSeg & 7) * 64 + lane] = cv.u;
                        a0 = 0.f; a1 = 0.f;
                        curSeg++;
                        segEnd = offsL[curSeg + 1];
                    }
                    union { bf162 h; unsigned int u; } uv; uv.u = vals[j];
                    a0 += __low2float(uv.h);
                    a1 += __high2float(uv.h);
                }
            }
        }
        // trailing flushes (last non-empty segment + empty tails)
        while (curSeg < segHi) {
            int b = offsL[curSeg], e2 = offsL[curSeg + 1];
            float inv = (e2 > b) ? 1.0f / (float)(e2 - b) : 0.0f;
            union { bf162 h; unsigned int u; } cv;
            cv.h = bf162(__float2bfloat16(a0 * inv), __float2bfloat16(a1 * inv));
            At[(curSeg >> 3) * (A_STRIDE / 2) + (curSeg & 7) * 64 + lane] = cv.u;
            a0 = 0.f; a1 = 0.f;
            curSeg++;
        }
    }
    __syncthreads();

    // ---- MFMA GEMM with B prefetch
    const int quad = lane >> 4, n15 = lane & 15;
    const int nt0 = 2 * w, nt1 = nt0 + 1;
    f32x4 acc0 = {0.f, 0.f, 0.f, 0.f};
    f32x4 acc1 = {0.f, 0.f, 0.f, 0.f};
    const short* Ash = (const short*)At;

    short8 b0 = Bp[(size_t)(nt0 * KC_CNT) * 64 + lane];
    short8 b1 = Bp[(size_t)(nt1 * KC_CNT) * 64 + lane];
#pragma unroll 4
    for (int kc = 0; kc < KC_CNT; kc++) {
        short8 cb0 = b0, cb1 = b1;
        if (kc + 1 < KC_CNT) {
            b0 = Bp[(size_t)(nt0 * KC_CNT + kc + 1) * 64 + lane];
            b1 = Bp[(size_t)(nt1 * KC_CNT + kc + 1) * 64 + lane];
        }
        short8 a = *reinterpret_cast<const short8*>(Ash + n15 * A_STRIDE + kc * 32 + quad * 8);
        acc0 = __builtin_amdgcn_mfma_f32_16x16x32_bf16(a, cb0, acc0, 0, 0, 0);
        acc1 = __builtin_amdgcn_mfma_f32_16x16x32_bf16(a, cb1, acc1, 0, 0, 0);
    }

    // epilogue: D[m = quad*4 + r][n = nt*16 + n15]
#pragma unroll
    for (int t2 = 0; t2 < 2; t2++) {
        int nt = t2 ? nt1 : nt0;
        f32x4 acc = t2 ? acc1 : acc0;
        int col = nt * 16 + n15;
        float bv = bias[col];
#pragma unroll
        for (int r = 0; r < 4; r++) {
            int m = quad * 4 + r;
            float v = acc[r] + bv;
            if (RELU) v = fmaxf(v, 0.f);
            if (OUT_F32) ((float*)outp)[(size_t)(v0 + m) * C + col] = v;
            else         ((bf16*)outp)[(size_t)(v0 + m) * C + col] = __float2bfloat16(v);
        }
    }
}

// ---------------------------------------------------------------- launch
// fp32 I/O. ZERO d_ws usage. Provenance:
//   d_out lo  : CSR build scratch (cnt/offs/partials/srcs)   [until mega done]
//   d_out hi  : x converted to bf16 (12.8 MB @ +8 MB)        [until layer 1 done]
//   ei buffer : final CSR (offs2 + srcs2, 5.6 MB)            [written after fill phase]
//   et buffer : packed weights Bp1/Bp2/b2p (0.6 MB)          [written after fill phase]
//   x buffer  : h1 bf16 (12.8 MB)                            [x fp32 dead after cvt]
//   d_out     : final fp32 output (layer 2 writes directly)
extern "C" void kernel_launch(void* const* d_in, const int* in_sizes, int n_in,
                              void* d_out, int out_size, void* d_ws, size_t ws_size,
                              hipStream_t stream) {
    const float* x     = (const float*)d_in[0];
    const int*   ei    = (const int*)d_in[1];
    const int*   et    = (const int*)d_in[2];
    const float* W1    = (const float*)d_in[3];
    const float* root1 = (const float*)d_in[4];
    const float* b1    = (const float*)d_in[5];
    const float* W2    = (const float*)d_in[6];
    const float* root2 = (const float*)d_in[7];
    const float* b2    = (const float*)d_in[8];
    const float* linW  = (const float*)d_in[9];
    const float* linb  = (const float*)d_in[10];

    // ---- d_out scratch
    char* ob = (char*)d_out;
    int* cnt_i    = (int*)(ob + 0);          // 1,600,000 B (then fill cursor)
    int* offs_t   = (int*)(ob + 1600256);    // 1,600,004 B
    int* partials = (int*)(ob + 3200512);
    int* pofs     = (int*)(ob + 3202176);
    int* srcs_t   = (int*)(ob + 3204096);    // 4,000,000 B -> ends 7,204,096
    unsigned int* xb16 = (unsigned int*)(ob + 8388608);  // 12.8 MB -> ends 21,188,608 < 25.6 MB

    // ---- ei buffer: final CSR
    char* eb = (char*)d_in[1];
    int* offs2 = (int*)(eb + 0);
    int* srcs2 = (int*)(eb + 1600256);       // ends 5,600,256 < 8 MB

    // ---- et buffer: packed weights
    char* tb = (char*)d_in[2];
    bf16*  Bp1 = (bf16*)(tb + 0);
    bf16*  Bp2 = (bf16*)(tb + 295168);
    float* b2p = (float*)(tb + 590336);      // ends < 4 MB

    unsigned int* h1 = (unsigned int*)d_in[0];   // layer-1 bf16 out -> x buffer
    float* out = (float*)d_out;

    MegaP p;
    p.xf = (const float2*)x; p.xb = xb16;
    p.src = ei; p.dst = ei + N_EDGES; p.et = et;
    p.cnt = cnt_i; p.offs = offs_t; p.partials = partials; p.pofs = pofs;
    p.srcs_t = srcs_t; p.offs2 = offs2; p.srcs2 = srcs2;
    p.W1 = W1; p.root1 = root1; p.W2 = W2; p.root2 = root2; p.linW = linW;
    p.b2 = b2; p.linb = linb;
    p.Bp1 = Bp1; p.Bp2 = Bp2; p.b2p = b2p;

    void* args[] = { (void*)&p };
    hipLaunchCooperativeKernel((const void*)mega_prep, dim3(1024), dim3(256),
                               args, 0, stream);

    fused_layer<1, 0><<<N_NODES / 16, 256, 0, stream>>>(
        xb16, offs2, srcs2, (const short8*)Bp1, b1, (void*)h1);
    fused_layer<0, 1><<<N_NODES / 16, 256, 0, stream>>>(
        h1, offs2, srcs2, (const short8*)Bp2, b2p, (void*)out);

    (void)in_sizes; (void)n_in; (void)out_size; (void)d_ws; (void)ws_size;
}

// Round 8
// 387.679 us; speedup vs baseline: 2.8341x; 2.8341x over previous
//
#include <hip/hip_runtime.h>
#include <hip/hip_bf16.h>

#define N_NODES 50000
#define N_EDGES 1000000
#define C       128
#define N_REL   8
#define N_SEG   (N_NODES * N_REL)       // 400000
#define KTOT    (N_REL * C + C)         // 1152 = 8 rel chunks + self
#define KC_CNT  (KTOT / 32)             // 36 MFMA k-chunks
#define A_STRIDE 1160                   // 1152 + 8 bf16 pad per row
#define NCHUNK  ((N_SEG + 1023) / 1024) // 391 scan chunks
#define MV_N    (N_SEG + 1 + N_EDGES)   // 1,400,001 ints to relocate

typedef __hip_bfloat16  bf16;
typedef __hip_bfloat162 bf162;
typedef __attribute__((ext_vector_type(8))) short short8;
typedef __attribute__((ext_vector_type(4))) float f32x4;

// ---------------------------------------------------------------- weight fragment index
// B-fragment for mfma_f32_16x16x32_bf16: lane = quad*16 + (n&15) holds
// B[k = kc*32 + quad*8 + j][n], j=0..7 contiguous.
__device__ __forceinline__ size_t frag_index(int k, int n) {
    int nt = n >> 4, n15 = n & 15;
    int kc = k >> 5, quad = (k >> 3) & 3, j = k & 7;
    int lane = quad * 16 + n15;
    return ((size_t)(nt * KC_CNT + kc) * 64 + lane) * 8 + j;
}

// ---------------------------------------------------------------- prep: x->bf16 cvt + seg count
#define CVT_BLOCKS ((N_NODES * C / 2) / 256)          // 12500 (exact)
#define CNT_BLOCKS ((N_EDGES + 255) / 256)            // 3907
__global__ void prep_kernel(const float2* __restrict__ xf, unsigned int* __restrict__ xb,
                            const int* __restrict__ dst, const int* __restrict__ et,
                            int* __restrict__ cnt) {
    int bid = blockIdx.x;
    if (bid < CVT_BLOCKS) {
        int i = bid * 256 + threadIdx.x;
        float2 v = xf[i];
        union { bf162 h; unsigned int u; } cv;
        cv.h = bf162(__float2bfloat16(v.x), __float2bfloat16(v.y));
        xb[i] = cv.u;
    } else {
        int e = (bid - CVT_BLOCKS) * 256 + threadIdx.x;
        if (e < N_EDGES) atomicAdd(&cnt[dst[e] * N_REL + et[e]], 1);
    }
}

// ---------------------------------------------------------------- scanA: chunk scans + weight repack
#define RP_B (KTOT * C / 256)             // 576 (exact)
__global__ void scanA_kernel(const int* __restrict__ cnt, int* __restrict__ offs,
                             int* __restrict__ partials,
                             const float* __restrict__ W1, const float* __restrict__ root1,
                             const float* __restrict__ W2, const float* __restrict__ root2,
                             const float* __restrict__ linW,
                             const float* __restrict__ b2, const float* __restrict__ linb,
                             bf16* __restrict__ Bp1, bf16* __restrict__ Bp2,
                             float* __restrict__ b2p) {
    int bid = blockIdx.x;
    int t   = threadIdx.x;
    if (bid < NCHUNK) {
        __shared__ int tot[256];
        int base = bid * 1024 + t * 4;
        int v0 = (base + 0 < N_SEG) ? cnt[base + 0] : 0;
        int v1 = (base + 1 < N_SEG) ? cnt[base + 1] : 0;
        int v2 = (base + 2 < N_SEG) ? cnt[base + 2] : 0;
        int v3 = (base + 3 < N_SEG) ? cnt[base + 3] : 0;
        int tsum = v0 + v1 + v2 + v3;
        tot[t] = tsum;
        __syncthreads();
        for (int d = 1; d < 256; d <<= 1) {
            int x = tot[t];
            int y = (t >= d) ? tot[t - d] : 0;
            __syncthreads();
            tot[t] = x + y;
            __syncthreads();
        }
        int excl = tot[t] - tsum;
        if (base + 0 < N_SEG) offs[base + 0] = excl;
        if (base + 1 < N_SEG) offs[base + 1] = excl + v0;
        if (base + 2 < N_SEG) offs[base + 2] = excl + v0 + v1;
        if (base + 3 < N_SEG) offs[base + 3] = excl + v0 + v1 + v2;
        if (t == 255) partials[bid] = tot[255];
    } else if (bid < NCHUNK + RP_B) {
        int idx = (bid - NCHUNK) * 256 + t;
        int k = idx >> 7, n = idx & 127;
        float val;
        if (k < N_REL * C) val = W1[(size_t)k * C + n];
        else               val = root1[(size_t)(k - N_REL * C) * C + n];
        Bp1[frag_index(k, n)] = __float2bfloat16(val);
    } else if (bid < NCHUNK + 2 * RP_B) {
        int idx = (bid - NCHUNK - RP_B) * 256 + t;
        int k = idx >> 7, n = idx & 127;
        const float* row = (k < N_REL * C) ? (W2 + (size_t)k * C)
                                           : (root2 + (size_t)(k - N_REL * C) * C);
        float acc = 0.f;
        for (int m = 0; m < C; m++)
            acc += row[m] * linW[(size_t)m * C + n];
        Bp2[frag_index(k, n)] = __float2bfloat16(acc);
    } else {
        if (t < 128) {
            float acc = linb[t];
            for (int m = 0; m < C; m++)
                acc += b2[m] * linW[(size_t)m * C + t];
            b2p[t] = acc;
        }
    }
}

// ---------------------------------------------------------------- scanB: merged scan2+scan3
// 512 threads; every block redundantly scans the 391 partials, applies its chunk.
__global__ void scanB_kernel(int* __restrict__ offs, const int* __restrict__ partials,
                             int* __restrict__ cur) {
    __shared__ int s[512];
    int t = threadIdx.x;
    int c = blockIdx.x;
    s[t] = (t < NCHUNK) ? partials[t] : 0;
    __syncthreads();
    for (int d = 1; d < 512; d <<= 1) {
        int x = s[t];
        int y = (t >= d) ? s[t - d] : 0;
        __syncthreads();
        s[t] = x + y;
        __syncthreads();
    }
    int add = (c == 0) ? 0 : s[c - 1];
    int base = c * 1024 + t * 2;
#pragma unroll
    for (int j = 0; j < 2; j++) {
        int idx = base + j;
        if (idx < N_SEG) {
            int v = offs[idx] + add;
            offs[idx] = v;
            cur[idx]  = v;
        }
    }
    if (c == 0 && t == 0) offs[N_SEG] = N_EDGES;
}

// ---------------------------------------------------------------- fill
__global__ void fill_kernel(const int* __restrict__ src, const int* __restrict__ dst,
                            const int* __restrict__ et, int* __restrict__ cur,
                            int* __restrict__ srcs) {
    int e = blockIdx.x * blockDim.x + threadIdx.x;
    if (e < N_EDGES) {
        int seg = dst[e] * N_REL + et[e];
        int pos = atomicAdd(&cur[seg], 1);
        srcs[pos] = src[e];
    }
}

// ---------------------------------------------------------------- fused layer
// Block: 16 nodes, 256 threads (4 waves). Wave w owns local segments
// [32w, 32w+32) (contiguous CSR edge range). 16-deep unconditional gather batches.
// COPY_CSR (layer 1 only): grid-stride copy of CSR into its final (ei-buffer) home.
template <int RELU, int OUT_F32, int COPY_CSR>
__global__ __launch_bounds__(256, 4) void fused_layer(
        const unsigned int* __restrict__ featu,  // [N][64] bf16 pairs
        const int*   __restrict__ offs,          // [N_SEG+1]
        const int*   __restrict__ srcs,          // [N_EDGES]
        const short8* __restrict__ Bp,           // fragment-packed bf16 weights
        const float* __restrict__ bias,          // [128] fp32
        void* __restrict__ outp,                 // [N][128] fp32 or bf16
        int* __restrict__ offs2, int* __restrict__ srcs2)   // CSR copy dst
{
    __shared__ __align__(16) unsigned int At[16 * (A_STRIDE / 2)];  // bf16 pairs
    __shared__ int offsL[129];
    const int tid  = threadIdx.x;
    const int lane = tid & 63;
    const int w    = tid >> 6;
    const int v0   = blockIdx.x * 16;

    if (tid < 129) offsL[tid] = offs[v0 * 8 + tid];
    if (tid < 64)  At[(tid >> 2) * (A_STRIDE / 2) + 576 + (tid & 3)] = 0u;  // pad pairs

    // relocate CSR slice (overlapped with gather latency)
    if (COPY_CSR) {
        for (int i = blockIdx.x * 256 + tid; i < MV_N; i += (N_NODES / 16) * 256) {
            if (i < N_SEG + 1) offs2[i] = offs[i];
            else               srcs2[i - (N_SEG + 1)] = srcs[i - (N_SEG + 1)];
        }
    }

    // self rows -> k range [1024..1151]
    for (int q = tid; q < 16 * 64; q += 256) {
        int node = q >> 6, pch = q & 63;
        At[node * (A_STRIDE / 2) + 512 + pch] = featu[(size_t)(v0 + node) * 64 + pch];
    }
    __syncthreads();

    // ---- aggregation over wave-owned contiguous edge range
    {
        const int segLo = w * 32;
        const int segHi = segLo + 32;
        int curSeg = segLo;
        int segEnd = offsL[curSeg + 1];
        int i      = offsL[segLo];
        const int eend = offsL[segHi];
        float a0 = 0.f, a1 = 0.f;

        while (i + 16 <= eend) {
            int sv[16];
#pragma unroll
            for (int j = 0; j < 16; j++) sv[j] = srcs[i + j];
            unsigned int vals[16];
#pragma unroll
            for (int j = 0; j < 16; j++) vals[j] = featu[(size_t)sv[j] * 64 + lane];
#pragma unroll
            for (int j = 0; j < 16; j++) {
                while (i + j == segEnd) {           // flush finished segment(s)
                    int b = offsL[curSeg];
                    float inv = (segEnd > b) ? 1.0f / (float)(segEnd - b) : 0.0f;
                    union { bf162 h; unsigned int u; } cv;
                    cv.h = bf162(__float2bfloat16(a0 * inv), __float2bfloat16(a1 * inv));
                    At[(curSeg >> 3) * (A_STRIDE / 2) + (curSeg & 7) * 64 + lane] = cv.u;
                    a0 = 0.f; a1 = 0.f;
                    curSeg++;
                    segEnd = offsL[curSeg + 1];
                }
                union { bf162 h; unsigned int u; } uv; uv.u = vals[j];
                a0 += __low2float(uv.h);
                a1 += __high2float(uv.h);
            }
            i += 16;
        }
        // predicated tail batch (m < 16, wave-uniform)
        {
            int m = eend - i;
            int sv[16];
#pragma unroll
            for (int j = 0; j < 16; j++) if (j < m) sv[j] = srcs[i + j];
            unsigned int vals[16];
#pragma unroll
            for (int j = 0; j < 16; j++) if (j < m) vals[j] = featu[(size_t)sv[j] * 64 + lane];
#pragma unroll
            for (int j = 0; j < 16; j++) {
                if (j < m) {
                    while (i + j == segEnd) {
                        int b = offsL[curSeg];
                        float inv = (segEnd > b) ? 1.0f / (float)(segEnd - b) : 0.0f;
                        union { bf162 h; unsigned int u; } cv;
                        cv.h = bf162(__float2bfloat16(a0 * inv), __float2bfloat16(a1 * inv));
                        At[(curSeg >> 3) * (A_STRIDE / 2) + (curSeg & 7) * 64 + lane] = cv.u;
                        a0 = 0.f; a1 = 0.f;
                        curSeg++;
                        segEnd = offsL[curSeg + 1];
                    }
                    union { bf162 h; unsigned int u; } uv; uv.u = vals[j];
                    a0 += __low2float(uv.h);
                    a1 += __high2float(uv.h);
                }
            }
        }
        // trailing flushes (last non-empty segment + empty tails)
        while (curSeg < segHi) {
            int b = offsL[curSeg], e2 = offsL[curSeg + 1];
            float inv = (e2 > b) ? 1.0f / (float)(e2 - b) : 0.0f;
            union { bf162 h; unsigned int u; } cv;
            cv.h = bf162(__float2bfloat16(a0 * inv), __float2bfloat16(a1 * inv));
            At[(curSeg >> 3) * (A_STRIDE / 2) + (curSeg & 7) * 64 + lane] = cv.u;
            a0 = 0.f; a1 = 0.f;
            curSeg++;
        }
    }
    __syncthreads();

    // ---- MFMA GEMM with B prefetch
    const int quad = lane >> 4, n15 = lane & 15;
    const int nt0 = 2 * w, nt1 = nt0 + 1;
    f32x4 acc0 = {0.f, 0.f, 0.f, 0.f};
    f32x4 acc1 = {0.f, 0.f, 0.f, 0.f};
    const short* Ash = (const short*)At;

    short8 b0 = Bp[(size_t)(nt0 * KC_CNT) * 64 + lane];
    short8 b1 = Bp[(size_t)(nt1 * KC_CNT) * 64 + lane];
#pragma unroll 4
    for (int kc = 0; kc < KC_CNT; kc++) {
        short8 cb0 = b0, cb1 = b1;
        if (kc + 1 < KC_CNT) {
            b0 = Bp[(size_t)(nt0 * KC_CNT + kc + 1) * 64 + lane];
            b1 = Bp[(size_t)(nt1 * KC_CNT + kc + 1) * 64 + lane];
        }
        short8 a = *reinterpret_cast<const short8*>(Ash + n15 * A_STRIDE + kc * 32 + quad * 8);
        acc0 = __builtin_amdgcn_mfma_f32_16x16x32_bf16(a, cb0, acc0, 0, 0, 0);
        acc1 = __builtin_amdgcn_mfma_f32_16x16x32_bf16(a, cb1, acc1, 0, 0, 0);
    }

    // epilogue: D[m = quad*4 + r][n = nt*16 + n15]
#pragma unroll
    for (int t2 = 0; t2 < 2; t2++) {
        int nt = t2 ? nt1 : nt0;
        f32x4 acc = t2 ? acc1 : acc0;
        int col = nt * 16 + n15;
        float bv = bias[col];
#pragma unroll
        for (int r = 0; r < 4; r++) {
            int m = quad * 4 + r;
            float v = acc[r] + bv;
            if (RELU) v = fmaxf(v, 0.f);
            if (OUT_F32) ((float*)outp)[(size_t)(v0 + m) * C + col] = v;
            else         ((bf16*)outp)[(size_t)(v0 + m) * C + col] = __float2bfloat16(v);
        }
    }
}

// ---------------------------------------------------------------- launch
// fp32 I/O. ZERO d_ws usage. Provenance:
//   d_out lo   : CSR build scratch (cnt/offs/partials/srcs)   [dead once layer 2 writes]
//   d_out hi   : x as bf16 (12.8 MB @ +8 MB)                  [dead after layer 1]
//   x buffer lo: h1 bf16 (12.8 MB)                            [x fp32 dead after cvt]
//   x buffer hi: packed weights Bp1/Bp2/b2p (@ +13.0 MB)      [written in scanA]
//   ei buffer  : final CSR (offs2+srcs2), copied BY layer 1   [ei dead after fill]
//   d_out      : final fp32 output (layer 2 writes directly)
extern "C" void kernel_launch(void* const* d_in, const int* in_sizes, int n_in,
                              void* d_out, int out_size, void* d_ws, size_t ws_size,
                              hipStream_t stream) {
    const float* x     = (const float*)d_in[0];
    const int*   ei    = (const int*)d_in[1];
    const int*   et    = (const int*)d_in[2];
    const float* W1    = (const float*)d_in[3];
    const float* root1 = (const float*)d_in[4];
    const float* b1    = (const float*)d_in[5];
    const float* W2    = (const float*)d_in[6];
    const float* root2 = (const float*)d_in[7];
    const float* b2    = (const float*)d_in[8];
    const float* linW  = (const float*)d_in[9];
    const float* linb  = (const float*)d_in[10];
    const int* src = ei;
    const int* dst = ei + N_EDGES;

    // ---- d_out scratch
    char* ob = (char*)d_out;
    int* cnt_i    = (int*)(ob + 0);          // 1,600,000 B (then fill cursor)
    int* offs_t   = (int*)(ob + 1600256);    // 1,600,004 B
    int* partials = (int*)(ob + 3200512);
    int* srcs_t   = (int*)(ob + 3204096);    // 4,000,000 B -> ends 7,204,096
    unsigned int* xb16 = (unsigned int*)(ob + 8388608);  // 12.8 MB -> ends 21,188,608 < 25.6 MB

    // ---- ei buffer: final CSR (written by layer 1's copy slice)
    char* eb = (char*)d_in[1];
    int* offs2 = (int*)(eb + 0);
    int* srcs2 = (int*)(eb + 1600256);       // ends 5,600,256 < 8 MB

    // ---- x buffer: h1 low, weights high
    char* xbuf = (char*)d_in[0];
    unsigned int* h1 = (unsigned int*)xbuf;          // 12.8 MB
    bf16*  Bp1 = (bf16*)(xbuf + 13000000);           // 294,912 B
    bf16*  Bp2 = (bf16*)(xbuf + 13295104);           // 294,912 B
    float* b2p = (float*)(xbuf + 13590016);          // 512 B -> ends < 25.6 MB

    float* out = (float*)d_out;

    hipMemsetAsync(cnt_i, 0, (size_t)N_SEG * 4, stream);
    prep_kernel<<<CVT_BLOCKS + CNT_BLOCKS, 256, 0, stream>>>(
        (const float2*)x, xb16, dst, et, cnt_i);
    scanA_kernel<<<NCHUNK + 2 * RP_B + 1, 256, 0, stream>>>(
        cnt_i, offs_t, partials, W1, root1, W2, root2, linW, b2, linb,
        Bp1, Bp2, b2p);
    scanB_kernel<<<NCHUNK, 512, 0, stream>>>(offs_t, partials, cnt_i);
    fill_kernel<<<(N_EDGES + 255) / 256, 256, 0, stream>>>(src, dst, et, cnt_i, srcs_t);

    fused_layer<1, 0, 1><<<N_NODES / 16, 256, 0, stream>>>(
        xb16, offs_t, srcs_t, (const short8*)Bp1, b1, (void*)h1, offs2, srcs2);
    fused_layer<0, 1, 0><<<N_NODES / 16, 256, 0, stream>>>(
        h1, offs2, srcs2, (const short8*)Bp2, b2p, (void*)out, nullptr, nullptr);

    (void)in_sizes; (void)n_in; (void)out_size; (void)d_ws; (void)ws_size;
}

// Round 9
// 335.772 us; speedup vs baseline: 3.2722x; 1.1546x over previous
//
#include <hip/hip_runtime.h>
#include <hip/hip_bf16.h>

#define N_NODES 50000
#define N_EDGES 1000000
#define C       128
#define N_REL   8
#define N_SEG   (N_NODES * N_REL)       // 400000
#define KTOT    (N_REL * C + C)         // 1152 = 8 rel chunks + self
#define KC_CNT  (KTOT / 32)             // 36 MFMA k-chunks
#define A_STRIDE 1160                   // 1152 + 8 bf16 pad per row
#define NCHUNK  ((N_SEG + 1023) / 1024) // 391 scan chunks
#define MV_N    (N_SEG + 1 + N_EDGES)   // 1,400,001 ints to relocate
#define NBLK    (N_NODES / 16)          // 3125 layer blocks

typedef __hip_bfloat16  bf16;
typedef __hip_bfloat162 bf162;
typedef __attribute__((ext_vector_type(8))) short short8;
typedef __attribute__((ext_vector_type(4))) float f32x4;

// ---------------------------------------------------------------- weight fragment index
// B-fragment for mfma_f32_16x16x32_bf16: lane = quad*16 + (n&15) holds
// B[k = kc*32 + quad*8 + j][n], j=0..7 contiguous.
__device__ __forceinline__ size_t frag_index(int k, int n) {
    int nt = n >> 4, n15 = n & 15;
    int kc = k >> 5, quad = (k >> 3) & 3, j = k & 7;
    int lane = quad * 16 + n15;
    return ((size_t)(nt * KC_CNT + kc) * 64 + lane) * 8 + j;
}

// ---------------------------------------------------------------- prep: x->bf16 cvt + seg count
#define CVT_BLOCKS ((N_NODES * C / 2) / 256)          // 12500 (exact)
#define CNT_BLOCKS ((N_EDGES + 255) / 256)            // 3907
__global__ void prep_kernel(const float2* __restrict__ xf, unsigned int* __restrict__ xb,
                            const int* __restrict__ dst, const int* __restrict__ et,
                            int* __restrict__ cnt) {
    int bid = blockIdx.x;
    if (bid < CVT_BLOCKS) {
        int i = bid * 256 + threadIdx.x;
        float2 v = xf[i];
        union { bf162 h; unsigned int u; } cv;
        cv.h = bf162(__float2bfloat16(v.x), __float2bfloat16(v.y));
        xb[i] = cv.u;
    } else {
        int e = (bid - CVT_BLOCKS) * 256 + threadIdx.x;
        if (e < N_EDGES) atomicAdd(&cnt[dst[e] * N_REL + et[e]], 1);
    }
}

// ---------------------------------------------------------------- scanA: chunk scans + weight repack
#define RP_B (KTOT * C / 256)             // 576 (exact)
__global__ void scanA_kernel(const int* __restrict__ cnt, int* __restrict__ offs,
                             int* __restrict__ partials,
                             const float* __restrict__ W1, const float* __restrict__ root1,
                             const float* __restrict__ W2, const float* __restrict__ root2,
                             const float* __restrict__ linW,
                             const float* __restrict__ b2, const float* __restrict__ linb,
                             bf16* __restrict__ Bp1, bf16* __restrict__ Bp2,
                             float* __restrict__ b2p) {
    int bid = blockIdx.x;
    int t   = threadIdx.x;
    if (bid < NCHUNK) {
        __shared__ int tot[256];
        int base = bid * 1024 + t * 4;
        int v0 = (base + 0 < N_SEG) ? cnt[base + 0] : 0;
        int v1 = (base + 1 < N_SEG) ? cnt[base + 1] : 0;
        int v2 = (base + 2 < N_SEG) ? cnt[base + 2] : 0;
        int v3 = (base + 3 < N_SEG) ? cnt[base + 3] : 0;
        int tsum = v0 + v1 + v2 + v3;
        tot[t] = tsum;
        __syncthreads();
        for (int d = 1; d < 256; d <<= 1) {
            int x = tot[t];
            int y = (t >= d) ? tot[t - d] : 0;
            __syncthreads();
            tot[t] = x + y;
            __syncthreads();
        }
        int excl = tot[t] - tsum;
        if (base + 0 < N_SEG) offs[base + 0] = excl;
        if (base + 1 < N_SEG) offs[base + 1] = excl + v0;
        if (base + 2 < N_SEG) offs[base + 2] = excl + v0 + v1;
        if (base + 3 < N_SEG) offs[base + 3] = excl + v0 + v1 + v2;
        if (t == 255) partials[bid] = tot[255];
    } else if (bid < NCHUNK + RP_B) {
        int idx = (bid - NCHUNK) * 256 + t;
        int k = idx >> 7, n = idx & 127;
        float val;
        if (k < N_REL * C) val = W1[(size_t)k * C + n];
        else               val = root1[(size_t)(k - N_REL * C) * C + n];
        Bp1[frag_index(k, n)] = __float2bfloat16(val);
    } else if (bid < NCHUNK + 2 * RP_B) {
        int idx = (bid - NCHUNK - RP_B) * 256 + t;
        int k = idx >> 7, n = idx & 127;
        const float* row = (k < N_REL * C) ? (W2 + (size_t)k * C)
                                           : (root2 + (size_t)(k - N_REL * C) * C);
        float acc = 0.f;
        for (int m = 0; m < C; m++)
            acc += row[m] * linW[(size_t)m * C + n];
        Bp2[frag_index(k, n)] = __float2bfloat16(acc);
    } else {
        if (t < 128) {
            float acc = linb[t];
            for (int m = 0; m < C; m++)
                acc += b2[m] * linW[(size_t)m * C + t];
            b2p[t] = acc;
        }
    }
}

// ---------------------------------------------------------------- scanB: merged scan2+scan3
__global__ void scanB_kernel(int* __restrict__ offs, const int* __restrict__ partials,
                             int* __restrict__ cur) {
    __shared__ int s[512];
    int t = threadIdx.x;
    int c = blockIdx.x;
    s[t] = (t < NCHUNK) ? partials[t] : 0;
    __syncthreads();
    for (int d = 1; d < 512; d <<= 1) {
        int x = s[t];
        int y = (t >= d) ? s[t - d] : 0;
        __syncthreads();
        s[t] = x + y;
        __syncthreads();
    }
    int add = (c == 0) ? 0 : s[c - 1];
    int base = c * 1024 + t * 2;
#pragma unroll
    for (int j = 0; j < 2; j++) {
        int idx = base + j;
        if (idx < N_SEG) {
            int v = offs[idx] + add;
            offs[idx] = v;
            cur[idx]  = v;
        }
    }
    if (c == 0 && t == 0) offs[N_SEG] = N_EDGES;
}

// ---------------------------------------------------------------- fill
__global__ void fill_kernel(const int* __restrict__ src, const int* __restrict__ dst,
                            const int* __restrict__ et, int* __restrict__ cur,
                            int* __restrict__ srcs) {
    int e = blockIdx.x * blockDim.x + threadIdx.x;
    if (e < N_EDGES) {
        int seg = dst[e] * N_REL + et[e];
        int pos = atomicAdd(&cur[seg], 1);
        srcs[pos] = src[e];
    }
}

// ---------------------------------------------------------------- fused layer
// Block: 16 nodes, 512 threads (8 waves). Wave w owns local segments
// [16w, 16w+16) = nodes 2w, 2w+1 (contiguous CSR edge range).
// 16-deep unconditional gather batches; srcs base forced wave-uniform (s_load).
// 4 blocks/CU (LDS-capped) x 512 thr = 2048 threads/CU = full occupancy.
template <int RELU, int OUT_F32, int COPY_CSR>
__global__ __launch_bounds__(512, 8) void fused_layer(
        const unsigned int* __restrict__ featu,  // [N][64] bf16 pairs
        const int*   __restrict__ offs,          // [N_SEG+1]
        const int*   __restrict__ srcs,          // [N_EDGES]
        const short8* __restrict__ Bp,           // fragment-packed bf16 weights
        const float* __restrict__ bias,          // [128] fp32
        void* __restrict__ outp,                 // [N][128] fp32 or bf16
        int* __restrict__ offs2, int* __restrict__ srcs2)   // CSR copy dst
{
    __shared__ __align__(16) unsigned int At[16 * (A_STRIDE / 2)];  // bf16 pairs
    __shared__ int offsL[129];
    const int tid  = threadIdx.x;
    const int lane = tid & 63;
    const int w    = tid >> 6;          // 0..7
    const int v0   = blockIdx.x * 16;

    if (tid < 129) offsL[tid] = offs[v0 * 8 + tid];
    if (tid < 64)  At[(tid >> 2) * (A_STRIDE / 2) + 576 + (tid & 3)] = 0u;  // pad pairs

    // relocate CSR slice (overlapped with gather latency)
    if (COPY_CSR) {
        for (int i = blockIdx.x * 512 + tid; i < MV_N; i += NBLK * 512) {
            if (i < N_SEG + 1) offs2[i] = offs[i];
            else               srcs2[i - (N_SEG + 1)] = srcs[i - (N_SEG + 1)];
        }
    }

    // self rows -> k range [1024..1151]
    for (int q = tid; q < 16 * 64; q += 512) {
        int node = q >> 6, pch = q & 63;
        At[node * (A_STRIDE / 2) + 512 + pch] = featu[(size_t)(v0 + node) * 64 + pch];
    }
    __syncthreads();

    // ---- aggregation over wave-owned contiguous edge range (16 segments)
    {
        const int segLo = w * 16;
        const int segHi = segLo + 16;
        int curSeg = segLo;
        int segEnd = offsL[curSeg + 1];
        int i      = offsL[segLo];
        const int eend = offsL[segHi];
        float a0 = 0.f, a1 = 0.f;

        while (i + 16 <= eend) {
            const int ib = __builtin_amdgcn_readfirstlane(i);   // uniform base -> s_load
            int sv[16];
#pragma unroll
            for (int j = 0; j < 16; j++) sv[j] = srcs[ib + j];
            unsigned int vals[16];
#pragma unroll
            for (int j = 0; j < 16; j++) vals[j] = featu[(size_t)sv[j] * 64 + lane];
#pragma unroll
            for (int j = 0; j < 16; j++) {
                while (i + j == segEnd) {           // flush finished segment(s)
                    int b = offsL[curSeg];
                    float inv = (segEnd > b) ? 1.0f / (float)(segEnd - b) : 0.0f;
                    union { bf162 h; unsigned int u; } cv;
                    cv.h = bf162(__float2bfloat16(a0 * inv), __float2bfloat16(a1 * inv));
                    At[(curSeg >> 3) * (A_STRIDE / 2) + (curSeg & 7) * 64 + lane] = cv.u;
                    a0 = 0.f; a1 = 0.f;
                    curSeg++;
                    segEnd = offsL[curSeg + 1];
                }
                union { bf162 h; unsigned int u; } uv; uv.u = vals[j];
                a0 += __low2float(uv.h);
                a1 += __high2float(uv.h);
            }
            i += 16;
        }
        // predicated tail batch (m < 16, wave-uniform)
        {
            int m = eend - i;
            const int ib = __builtin_amdgcn_readfirstlane(i);
            int sv[16];
#pragma unroll
            for (int j = 0; j < 16; j++) if (j < m) sv[j] = srcs[ib + j];
            unsigned int vals[16];
#pragma unroll
            for (int j = 0; j < 16; j++) if (j < m) vals[j] = featu[(size_t)sv[j] * 64 + lane];
#pragma unroll
            for (int j = 0; j < 16; j++) {
                if (j < m) {
                    while (i + j == segEnd) {
                        int b = offsL[curSeg];
                        float inv = (segEnd > b) ? 1.0f / (float)(segEnd - b) : 0.0f;
                        union { bf162 h; unsigned int u; } cv;
                        cv.h = bf162(__float2bfloat16(a0 * inv), __float2bfloat16(a1 * inv));
                        At[(curSeg >> 3) * (A_STRIDE / 2) + (curSeg & 7) * 64 + lane] = cv.u;
                        a0 = 0.f; a1 = 0.f;
                        curSeg++;
                        segEnd = offsL[curSeg + 1];
                    }
                    union { bf162 h; unsigned int u; } uv; uv.u = vals[j];
                    a0 += __low2float(uv.h);
                    a1 += __high2float(uv.h);
                }
            }
        }
        // trailing flushes (last non-empty segment + empty tails)
        while (curSeg < segHi) {
            int b = offsL[curSeg], e2 = offsL[curSeg + 1];
            float inv = (e2 > b) ? 1.0f / (float)(e2 - b) : 0.0f;
            union { bf162 h; unsigned int u; } cv;
            cv.h = bf162(__float2bfloat16(a0 * inv), __float2bfloat16(a1 * inv));
            At[(curSeg >> 3) * (A_STRIDE / 2) + (curSeg & 7) * 64 + lane] = cv.u;
            a0 = 0.f; a1 = 0.f;
            curSeg++;
        }
    }
    __syncthreads();

    // ---- MFMA GEMM: wave w computes N-tile w (cols 16w..16w+15)
    const int quad = lane >> 4, n15 = lane & 15;
    f32x4 acc = {0.f, 0.f, 0.f, 0.f};
    const short* Ash = (const short*)At;

    short8 b0 = Bp[(size_t)(w * KC_CNT) * 64 + lane];
#pragma unroll 4
    for (int kc = 0; kc < KC_CNT; kc++) {
        short8 cb0 = b0;
        if (kc + 1 < KC_CNT)
            b0 = Bp[(size_t)(w * KC_CNT + kc + 1) * 64 + lane];
        short8 a = *reinterpret_cast<const short8*>(Ash + n15 * A_STRIDE + kc * 32 + quad * 8);
        acc = __builtin_amdgcn_mfma_f32_16x16x32_bf16(a, cb0, acc, 0, 0, 0);
    }

    // epilogue: D[m = quad*4 + r][col = w*16 + n15]
    {
        int col = w * 16 + n15;
        float bv = bias[col];
#pragma unroll
        for (int r = 0; r < 4; r++) {
            int m = quad * 4 + r;
            float v = acc[r] + bv;
            if (RELU) v = fmaxf(v, 0.f);
            if (OUT_F32) ((float*)outp)[(size_t)(v0 + m) * C + col] = v;
            else         ((bf16*)outp)[(size_t)(v0 + m) * C + col] = __float2bfloat16(v);
        }
    }
}

// ---------------------------------------------------------------- launch
// fp32 I/O. ZERO d_ws usage. Provenance:
//   d_out lo   : CSR build scratch (cnt/offs/partials/srcs)   [dead once layer 2 writes]
//   d_out hi   : x as bf16 (12.8 MB @ +8 MB)                  [dead after layer 1]
//   x buffer lo: h1 bf16 (12.8 MB)                            [x fp32 dead after cvt]
//   x buffer hi: packed weights Bp1/Bp2/b2p (@ +13.0 MB)      [written in scanA]
//   ei buffer  : final CSR (offs2+srcs2), copied BY layer 1   [ei dead after fill]
//   d_out      : final fp32 output (layer 2 writes directly)
extern "C" void kernel_launch(void* const* d_in, const int* in_sizes, int n_in,
                              void* d_out, int out_size, void* d_ws, size_t ws_size,
                              hipStream_t stream) {
    const float* x     = (const float*)d_in[0];
    const int*   ei    = (const int*)d_in[1];
    const int*   et    = (const int*)d_in[2];
    const float* W1    = (const float*)d_in[3];
    const float* root1 = (const float*)d_in[4];
    const float* b1    = (const float*)d_in[5];
    const float* W2    = (const float*)d_in[6];
    const float* root2 = (const float*)d_in[7];
    const float* b2    = (const float*)d_in[8];
    const float* linW  = (const float*)d_in[9];
    const float* linb  = (const float*)d_in[10];
    const int* src = ei;
    const int* dst = ei + N_EDGES;

    // ---- d_out scratch
    char* ob = (char*)d_out;
    int* cnt_i    = (int*)(ob + 0);          // 1,600,000 B (then fill cursor)
    int* offs_t   = (int*)(ob + 1600256);    // 1,600,004 B
    int* partials = (int*)(ob + 3200512);
    int* srcs_t   = (int*)(ob + 3204096);    // 4,000,000 B -> ends 7,204,096
    unsigned int* xb16 = (unsigned int*)(ob + 8388608);  // 12.8 MB -> ends 21,188,608 < 25.6 MB

    // ---- ei buffer: final CSR (written by layer 1's copy slice)
    char* eb = (char*)d_in[1];
    int* offs2 = (int*)(eb + 0);
    int* srcs2 = (int*)(eb + 1600256);       // ends 5,600,256 < 8 MB

    // ---- x buffer: h1 low, weights high
    char* xbuf = (char*)d_in[0];
    unsigned int* h1 = (unsigned int*)xbuf;          // 12.8 MB
    bf16*  Bp1 = (bf16*)(xbuf + 13000000);           // 294,912 B
    bf16*  Bp2 = (bf16*)(xbuf + 13295104);           // 294,912 B
    float* b2p = (float*)(xbuf + 13590016);          // 512 B -> ends < 25.6 MB

    float* out = (float*)d_out;

    hipMemsetAsync(cnt_i, 0, (size_t)N_SEG * 4, stream);
    prep_kernel<<<CVT_BLOCKS + CNT_BLOCKS, 256, 0, stream>>>(
        (const float2*)x, xb16, dst, et, cnt_i);
    scanA_kernel<<<NCHUNK + 2 * RP_B + 1, 256, 0, stream>>>(
        cnt_i, offs_t, partials, W1, root1, W2, root2, linW, b2, linb,
        Bp1, Bp2, b2p);
    scanB_kernel<<<NCHUNK, 512, 0, stream>>>(offs_t, partials, cnt_i);
    fill_kernel<<<(N_EDGES + 255) / 256, 256, 0, stream>>>(src, dst, et, cnt_i, srcs_t);

    fused_layer<1, 0, 1><<<NBLK, 512, 0, stream>>>(
        xb16, offs_t, srcs_t, (const short8*)Bp1, b1, (void*)h1, offs2, srcs2);
    fused_layer<0, 1, 0><<<NBLK, 512, 0, stream>>>(
        h1, offs2, srcs2, (const short8*)Bp2, b2p, (void*)out, nullptr, nullptr);

    (void)in_sizes; (void)n_in; (void)out_size; (void)d_ws; (void)ws_size;
}

// Round 10
// 332.754 us; speedup vs baseline: 3.3019x; 1.0091x over previous
//
#include <hip/hip_runtime.h>
#include <hip/hip_bf16.h>

#define N_NODES 50000
#define N_EDGES 1000000
#define C       128
#define N_REL   8
#define N_SEG   (N_NODES * N_REL)       // 400000
#define KTOT    (N_REL * C + C)         // 1152 = 8 rel chunks + self
#define KC_CNT  (KTOT / 32)             // 36 MFMA k-chunks
#define A_STRIDE 1160                   // 1152 + 8 bf16 pad per row
#define NCHUNK  ((N_SEG + 1023) / 1024) // 391 scan chunks
#define MV_N    (N_SEG + 1 + N_EDGES)   // 1,400,001 ints to relocate
#define NBLK    (N_NODES / 16)          // 3125 layer blocks
#define FE_BLK  ((N_EDGES + 511) / 512) // 1954 fill edge-blocks

typedef __hip_bfloat16  bf16;
typedef __hip_bfloat162 bf162;
typedef __attribute__((ext_vector_type(8))) short short8;
typedef __attribute__((ext_vector_type(4))) float f32x4;

// ---------------------------------------------------------------- weight fragment index
// B-fragment for mfma_f32_16x16x32_bf16: lane = quad*16 + (n&15) holds
// B[k = kc*32 + quad*8 + j][n], j=0..7 contiguous.
__device__ __forceinline__ size_t frag_index(int k, int n) {
    int nt = n >> 4, n15 = n & 15;
    int kc = k >> 5, quad = (k >> 3) & 3, j = k & 7;
    int lane = quad * 16 + n15;
    return ((size_t)(nt * KC_CNT + kc) * 64 + lane) * 8 + j;
}

// ---------------------------------------------------------------- prep: x->bf16 cvt + seg count
#define CVT_BLOCKS ((N_NODES * C / 2) / 256)          // 12500 (exact)
#define CNT_BLOCKS ((N_EDGES + 255) / 256)            // 3907
__global__ void prep_kernel(const float2* __restrict__ xf, unsigned int* __restrict__ xb,
                            const int* __restrict__ dst, const int* __restrict__ et,
                            int* __restrict__ cnt) {
    int bid = blockIdx.x;
    if (bid < CVT_BLOCKS) {
        int i = bid * 256 + threadIdx.x;
        float2 v = xf[i];
        union { bf162 h; unsigned int u; } cv;
        cv.h = bf162(__float2bfloat16(v.x), __float2bfloat16(v.y));
        xb[i] = cv.u;
    } else {
        int e = (bid - CVT_BLOCKS) * 256 + threadIdx.x;
        if (e < N_EDGES) atomicAdd(&cnt[dst[e] * N_REL + et[e]], 1);
    }
}

// ---------------------------------------------------------------- scanA: chunk scans + weight repack
#define RP_B (KTOT * C / 256)             // 576 (exact)
__global__ void scanA_kernel(const int* __restrict__ cnt, int* __restrict__ offs,
                             int* __restrict__ partials,
                             const float* __restrict__ W1, const float* __restrict__ root1,
                             const float* __restrict__ W2, const float* __restrict__ root2,
                             const float* __restrict__ linW,
                             const float* __restrict__ b2, const float* __restrict__ linb,
                             bf16* __restrict__ Bp1, bf16* __restrict__ Bp2,
                             float* __restrict__ b2p) {
    int bid = blockIdx.x;
    int t   = threadIdx.x;
    if (bid < NCHUNK) {
        __shared__ int tot[256];
        int base = bid * 1024 + t * 4;
        int v0 = (base + 0 < N_SEG) ? cnt[base + 0] : 0;
        int v1 = (base + 1 < N_SEG) ? cnt[base + 1] : 0;
        int v2 = (base + 2 < N_SEG) ? cnt[base + 2] : 0;
        int v3 = (base + 3 < N_SEG) ? cnt[base + 3] : 0;
        int tsum = v0 + v1 + v2 + v3;
        tot[t] = tsum;
        __syncthreads();
        for (int d = 1; d < 256; d <<= 1) {
            int x = tot[t];
            int y = (t >= d) ? tot[t - d] : 0;
            __syncthreads();
            tot[t] = x + y;
            __syncthreads();
        }
        int excl = tot[t] - tsum;
        if (base + 0 < N_SEG) offs[base + 0] = excl;
        if (base + 1 < N_SEG) offs[base + 1] = excl + v0;
        if (base + 2 < N_SEG) offs[base + 2] = excl + v0 + v1;
        if (base + 3 < N_SEG) offs[base + 3] = excl + v0 + v1 + v2;
        if (t == 255) partials[bid] = tot[255];
    } else if (bid < NCHUNK + RP_B) {
        int idx = (bid - NCHUNK) * 256 + t;
        int k = idx >> 7, n = idx & 127;
        float val;
        if (k < N_REL * C) val = W1[(size_t)k * C + n];
        else               val = root1[(size_t)(k - N_REL * C) * C + n];
        Bp1[frag_index(k, n)] = __float2bfloat16(val);
    } else if (bid < NCHUNK + 2 * RP_B) {
        int idx = (bid - NCHUNK - RP_B) * 256 + t;
        int k = idx >> 7, n = idx & 127;
        const float* row = (k < N_REL * C) ? (W2 + (size_t)k * C)
                                           : (root2 + (size_t)(k - N_REL * C) * C);
        float acc = 0.f;
        for (int m = 0; m < C; m++)
            acc += row[m] * linW[(size_t)m * C + n];
        Bp2[frag_index(k, n)] = __float2bfloat16(acc);
    } else {
        if (t < 128) {
            float acc = linb[t];
            for (int m = 0; m < C; m++)
                acc += b2[m] * linW[(size_t)m * C + t];
            b2p[t] = acc;
        }
    }
}

// ---------------------------------------------------------------- fillB: offs finalize + edge fill
// 512 threads. Every block scans the 391 partials in LDS.
// Blocks [0, NCHUNK): write final offs (+sentinel).
// Blocks [NCHUNK, NCHUNK+FE_BLK): per-edge pos = offs_raw[seg] + chunk_base + ticket.
__global__ void fillB_kernel(const int* __restrict__ src, const int* __restrict__ dst,
                             const int* __restrict__ et,
                             const int* __restrict__ offs_raw,   // scanA output
                             const int* __restrict__ partials,
                             int* __restrict__ offs_final,
                             int* __restrict__ ticket,           // zeroed [N_SEG]
                             int* __restrict__ srcs_out) {
    __shared__ int s[512];
    int t = threadIdx.x;
    int bid = blockIdx.x;
    s[t] = (t < NCHUNK) ? partials[t] : 0;
    __syncthreads();
    for (int d = 1; d < 512; d <<= 1) {
        int x = s[t];
        int y = (t >= d) ? s[t - d] : 0;
        __syncthreads();
        s[t] = x + y;          // inclusive scan
        __syncthreads();
    }
    if (bid < NCHUNK) {
        int add = (bid == 0) ? 0 : s[bid - 1];
        int base = bid * 1024 + t * 2;
#pragma unroll
        for (int j = 0; j < 2; j++) {
            int idx = base + j;
            if (idx < N_SEG) offs_final[idx] = offs_raw[idx] + add;
        }
        if (bid == 0 && t == 0) offs_final[N_SEG] = N_EDGES;
    } else {
        int e = (bid - NCHUNK) * 512 + t;
        if (e < N_EDGES) {
            int seg = dst[e] * N_REL + et[e];
            int chunk = seg >> 10;
            int base = offs_raw[seg] + ((chunk == 0) ? 0 : s[chunk - 1]);
            int pos = base + atomicAdd(&ticket[seg], 1);
            srcs_out[pos] = src[e];
        }
    }
}

// ---------------------------------------------------------------- fused layer
// Block: 16 nodes, 512 threads (8 waves). Wave w owns local segments
// [16w, 16w+16) = nodes 2w, 2w+1 (contiguous CSR edge range).
// 16-deep unconditional gather batches; srcs base wave-uniform (s_load).
// launch_bounds(512, 6): VGPR cap ~85 so the 16 gathers stay co-resident
// (R9's (512,8) cap=64 forced VGPR 28 -> serialized loads). LDS still the
// occupancy limiter (~24 waves/CU == R9's observed 23) -> pure MLP gain.
template <int RELU, int OUT_F32, int COPY_CSR>
__global__ __launch_bounds__(512, 6) void fused_layer(
        const unsigned int* __restrict__ featu,  // [N][64] bf16 pairs
        const int*   __restrict__ offs,          // [N_SEG+1]
        const int*   __restrict__ srcs,          // [N_EDGES]
        const short8* __restrict__ Bp,           // fragment-packed bf16 weights
        const float* __restrict__ bias,          // [128] fp32
        void* __restrict__ outp,                 // [N][128] fp32 or bf16
        int* __restrict__ offs2, int* __restrict__ srcs2)   // CSR copy dst
{
    __shared__ __align__(16) unsigned int At[16 * (A_STRIDE / 2)];  // bf16 pairs
    __shared__ int offsL[129];
    const int tid  = threadIdx.x;
    const int lane = tid & 63;
    const int w    = tid >> 6;          // 0..7
    const int v0   = blockIdx.x * 16;

    if (tid < 129) offsL[tid] = offs[v0 * 8 + tid];
    if (tid < 64)  At[(tid >> 2) * (A_STRIDE / 2) + 576 + (tid & 3)] = 0u;  // pad pairs

    // relocate CSR slice (overlapped with gather latency)
    if (COPY_CSR) {
        for (int i = blockIdx.x * 512 + tid; i < MV_N; i += NBLK * 512) {
            if (i < N_SEG + 1) offs2[i] = offs[i];
            else               srcs2[i - (N_SEG + 1)] = srcs[i - (N_SEG + 1)];
        }
    }

    // self rows -> k range [1024..1151]
    for (int q = tid; q < 16 * 64; q += 512) {
        int node = q >> 6, pch = q & 63;
        At[node * (A_STRIDE / 2) + 512 + pch] = featu[(size_t)(v0 + node) * 64 + pch];
    }
    __syncthreads();

    // ---- aggregation over wave-owned contiguous edge range (16 segments)
    {
        const int segLo = w * 16;
        const int segHi = segLo + 16;
        int curSeg = segLo;
        int segEnd = offsL[curSeg + 1];
        int i      = offsL[segLo];
        const int eend = offsL[segHi];
        float a0 = 0.f, a1 = 0.f;

        while (i + 16 <= eend) {
            const int ib = __builtin_amdgcn_readfirstlane(i);   // uniform base -> s_load
            int sv[16];
#pragma unroll
            for (int j = 0; j < 16; j++) sv[j] = srcs[ib + j];
            unsigned int vals[16];
#pragma unroll
            for (int j = 0; j < 16; j++) vals[j] = featu[(size_t)sv[j] * 64 + lane];
#pragma unroll
            for (int j = 0; j < 16; j++) {
                while (i + j == segEnd) {           // flush finished segment(s)
                    int b = offsL[curSeg];
                    float inv = (segEnd > b) ? 1.0f / (float)(segEnd - b) : 0.0f;
                    union { bf162 h; unsigned int u; } cv;
                    cv.h = bf162(__float2bfloat16(a0 * inv), __float2bfloat16(a1 * inv));
                    At[(curSeg >> 3) * (A_STRIDE / 2) + (curSeg & 7) * 64 + lane] = cv.u;
                    a0 = 0.f; a1 = 0.f;
                    curSeg++;
                    segEnd = offsL[curSeg + 1];
                }
                union { bf162 h; unsigned int u; } uv; uv.u = vals[j];
                a0 += __low2float(uv.h);
                a1 += __high2float(uv.h);
            }
            i += 16;
        }
        // predicated tail batch (m < 16, wave-uniform)
        {
            int m = eend - i;
            const int ib = __builtin_amdgcn_readfirstlane(i);
            int sv[16];
#pragma unroll
            for (int j = 0; j < 16; j++) if (j < m) sv[j] = srcs[ib + j];
            unsigned int vals[16];
#pragma unroll
            for (int j = 0; j < 16; j++) if (j < m) vals[j] = featu[(size_t)sv[j] * 64 + lane];
#pragma unroll
            for (int j = 0; j < 16; j++) {
                if (j < m) {
                    while (i + j == segEnd) {
                        int b = offsL[curSeg];
                        float inv = (segEnd > b) ? 1.0f / (float)(segEnd - b) : 0.0f;
                        union { bf162 h; unsigned int u; } cv;
                        cv.h = bf162(__float2bfloat16(a0 * inv), __float2bfloat16(a1 * inv));
                        At[(curSeg >> 3) * (A_STRIDE / 2) + (curSeg & 7) * 64 + lane] = cv.u;
                        a0 = 0.f; a1 = 0.f;
                        curSeg++;
                        segEnd = offsL[curSeg + 1];
                    }
                    union { bf162 h; unsigned int u; } uv; uv.u = vals[j];
                    a0 += __low2float(uv.h);
                    a1 += __high2float(uv.h);
                }
            }
        }
        // trailing flushes (last non-empty segment + empty tails)
        while (curSeg < segHi) {
            int b = offsL[curSeg], e2 = offsL[curSeg + 1];
            float inv = (e2 > b) ? 1.0f / (float)(e2 - b) : 0.0f;
            union { bf162 h; unsigned int u; } cv;
            cv.h = bf162(__float2bfloat16(a0 * inv), __float2bfloat16(a1 * inv));
            At[(curSeg >> 3) * (A_STRIDE / 2) + (curSeg & 7) * 64 + lane] = cv.u;
            a0 = 0.f; a1 = 0.f;
            curSeg++;
        }
    }
    __syncthreads();

    // ---- MFMA GEMM: wave w computes N-tile w (cols 16w..16w+15)
    const int quad = lane >> 4, n15 = lane & 15;
    f32x4 acc = {0.f, 0.f, 0.f, 0.f};
    const short* Ash = (const short*)At;

    short8 b0 = Bp[(size_t)(w * KC_CNT) * 64 + lane];
#pragma unroll 4
    for (int kc = 0; kc < KC_CNT; kc++) {
        short8 cb0 = b0;
        if (kc + 1 < KC_CNT)
            b0 = Bp[(size_t)(w * KC_CNT + kc + 1) * 64 + lane];
        short8 a = *reinterpret_cast<const short8*>(Ash + n15 * A_STRIDE + kc * 32 + quad * 8);
        acc = __builtin_amdgcn_mfma_f32_16x16x32_bf16(a, cb0, acc, 0, 0, 0);
    }

    // epilogue: D[m = quad*4 + r][col = w*16 + n15]
    {
        int col = w * 16 + n15;
        float bv = bias[col];
#pragma unroll
        for (int r = 0; r < 4; r++) {
            int m = quad * 4 + r;
            float v = acc[r] + bv;
            if (RELU) v = fmaxf(v, 0.f);
            if (OUT_F32) ((float*)outp)[(size_t)(v0 + m) * C + col] = v;
            else         ((bf16*)outp)[(size_t)(v0 + m) * C + col] = __float2bfloat16(v);
        }
    }
}

// ---------------------------------------------------------------- launch
// fp32 I/O. ZERO d_ws usage. Provenance:
//   d_out lo   : CSR scratch (cnt/ticket/offs_raw/partials/srcs/offs_final)
//   d_out hi   : x as bf16 (12.8 MB @ +9 MB)                  [dead after layer 1]
//   x buffer lo: h1 bf16 (12.8 MB)                            [x fp32 dead after cvt]
//   x buffer hi: packed weights Bp1/Bp2/b2p (@ +13.0 MB)      [written in scanA]
//   ei buffer  : final CSR (offs2+srcs2), copied BY layer 1   [ei dead after fillB]
//   d_out      : final fp32 output (layer 2 writes directly)
extern "C" void kernel_launch(void* const* d_in, const int* in_sizes, int n_in,
                              void* d_out, int out_size, void* d_ws, size_t ws_size,
                              hipStream_t stream) {
    const float* x     = (const float*)d_in[0];
    const int*   ei    = (const int*)d_in[1];
    const int*   et    = (const int*)d_in[2];
    const float* W1    = (const float*)d_in[3];
    const float* root1 = (const float*)d_in[4];
    const float* b1    = (const float*)d_in[5];
    const float* W2    = (const float*)d_in[6];
    const float* root2 = (const float*)d_in[7];
    const float* b2    = (const float*)d_in[8];
    const float* linW  = (const float*)d_in[9];
    const float* linb  = (const float*)d_in[10];
    const int* src = ei;
    const int* dst = ei + N_EDGES;

    // ---- d_out scratch
    char* ob = (char*)d_out;
    int* cnt_i    = (int*)(ob + 0);          // 1,600,000 B
    int* ticket   = (int*)(ob + 1600000);    // 1,600,000 B (memset covers both)
    int* offs_t   = (int*)(ob + 3200000);    // 1,600,004 B (raw chunk-local scans)
    int* partials = (int*)(ob + 4800256);    // 1,564 B
    int* offs_f   = (int*)(ob + 4803072);    // 1,600,004 B (final offs)
    int* srcs_t   = (int*)(ob + 6403328);    // 4,000,000 B -> ends 10,403,328
    unsigned int* xb16 = (unsigned int*)(ob + 10500000); // 12.8 MB -> ends 23,300,000 < 25.6 MB

    // ---- ei buffer: final CSR (written by layer 1's copy slice)
    char* eb = (char*)d_in[1];
    int* offs2 = (int*)(eb + 0);
    int* srcs2 = (int*)(eb + 1600256);       // ends 5,600,256 < 8 MB

    // ---- x buffer: h1 low, weights high
    char* xbuf = (char*)d_in[0];
    unsigned int* h1 = (unsigned int*)xbuf;          // 12.8 MB
    bf16*  Bp1 = (bf16*)(xbuf + 13000000);           // 294,912 B
    bf16*  Bp2 = (bf16*)(xbuf + 13295104);           // 294,912 B
    float* b2p = (float*)(xbuf + 13590016);          // 512 B -> ends < 25.6 MB

    float* out = (float*)d_out;

    hipMemsetAsync(cnt_i, 0, 3200000, stream);   // cnt + ticket
    prep_kernel<<<CVT_BLOCKS + CNT_BLOCKS, 256, 0, stream>>>(
        (const float2*)x, xb16, dst, et, cnt_i);
    scanA_kernel<<<NCHUNK + 2 * RP_B + 1, 256, 0, stream>>>(
        cnt_i, offs_t, partials, W1, root1, W2, root2, linW, b2, linb,
        Bp1, Bp2, b2p);
    fillB_kernel<<<NCHUNK + FE_BLK, 512, 0, stream>>>(
        src, dst, et, offs_t, partials, offs_f, ticket, srcs_t);

    fused_layer<1, 0, 1><<<NBLK, 512, 0, stream>>>(
        xb16, offs_f, srcs_t, (const short8*)Bp1, b1, (void*)h1, offs2, srcs2);
    fused_layer<0, 1, 0><<<NBLK, 512, 0, stream>>>(
        h1, offs2, srcs2, (const short8*)Bp2, b2p, (void*)out, nullptr, nullptr);

    (void)in_sizes; (void)n_in; (void)out_size; (void)d_ws; (void)ws_size;
}

// Round 11
// 327.142 us; speedup vs baseline: 3.3586x; 1.0172x over previous
//
#include <hip/hip_runtime.h>
#include <hip/hip_bf16.h>

#define N_NODES 50000
#define N_EDGES 1000000
#define C       128
#define N_REL   8
#define N_SEG   (N_NODES * N_REL)       // 400000
#define KTOT    (N_REL * C + C)         // 1152 = 8 rel chunks + self
#define KC_CNT  (KTOT / 32)             // 36 MFMA k-chunks
#define A_STRIDE 1160                   // 1152 + 8 bf16 pad per row
#define NCHUNK  ((N_SEG + 1023) / 1024) // 391 scan chunks
#define MV_N    (N_SEG + 1 + N_EDGES)   // 1,400,001 ints to relocate
#define NBLK    (N_NODES / 16)          // 3125 layer blocks
#define FE_BLK  ((N_EDGES + 511) / 512) // 1954 fill edge-blocks

typedef __hip_bfloat16  bf16;
typedef __hip_bfloat162 bf162;
typedef __attribute__((ext_vector_type(8))) short short8;
typedef __attribute__((ext_vector_type(4))) float f32x4;

// ---------------------------------------------------------------- weight fragment index
// B-fragment for mfma_f32_16x16x32_bf16: lane = quad*16 + (n&15) holds
// B[k = kc*32 + quad*8 + j][n], j=0..7 contiguous.
__device__ __forceinline__ size_t frag_index(int k, int n) {
    int nt = n >> 4, n15 = n & 15;
    int kc = k >> 5, quad = (k >> 3) & 3, j = k & 7;
    int lane = quad * 16 + n15;
    return ((size_t)(nt * KC_CNT + kc) * 64 + lane) * 8 + j;
}

// ---------------------------------------------------------------- prep: x->bf16 cvt + seg count
#define CVT_BLOCKS ((N_NODES * C / 2) / 256)          // 12500 (exact)
#define CNT_BLOCKS ((N_EDGES + 255) / 256)            // 3907
__global__ void prep_kernel(const float2* __restrict__ xf, unsigned int* __restrict__ xb,
                            const int* __restrict__ dst, const int* __restrict__ et,
                            int* __restrict__ cnt) {
    int bid = blockIdx.x;
    if (bid < CVT_BLOCKS) {
        int i = bid * 256 + threadIdx.x;
        float2 v = xf[i];
        union { bf162 h; unsigned int u; } cv;
        cv.h = bf162(__float2bfloat16(v.x), __float2bfloat16(v.y));
        xb[i] = cv.u;
    } else {
        int e = (bid - CVT_BLOCKS) * 256 + threadIdx.x;
        if (e < N_EDGES) atomicAdd(&cnt[dst[e] * N_REL + et[e]], 1);
    }
}

// ---------------------------------------------------------------- scanA: chunk scans + weight repack
// repack1: plain copy (RP_B blocks).  repack2: tiled GEMM W2cat x linW
// (RPT_B blocks of 16x16 output tiles, staged via LDS -> coalesced).
#define RP_B  (KTOT * C / 256)            // 576
#define RPT_B ((KTOT / 16) * (C / 16))    // 72 * 8 = 576
__global__ void scanA_kernel(const int* __restrict__ cnt, int* __restrict__ offs,
                             int* __restrict__ partials,
                             const float* __restrict__ W1, const float* __restrict__ root1,
                             const float* __restrict__ W2, const float* __restrict__ root2,
                             const float* __restrict__ linW,
                             const float* __restrict__ b2, const float* __restrict__ linb,
                             bf16* __restrict__ Bp1, bf16* __restrict__ Bp2,
                             float* __restrict__ b2p) {
    int bid = blockIdx.x;
    int t   = threadIdx.x;
    if (bid < NCHUNK) {
        __shared__ int tot[256];
        int base = bid * 1024 + t * 4;
        int v0 = (base + 0 < N_SEG) ? cnt[base + 0] : 0;
        int v1 = (base + 1 < N_SEG) ? cnt[base + 1] : 0;
        int v2 = (base + 2 < N_SEG) ? cnt[base + 2] : 0;
        int v3 = (base + 3 < N_SEG) ? cnt[base + 3] : 0;
        int tsum = v0 + v1 + v2 + v3;
        tot[t] = tsum;
        __syncthreads();
        for (int d = 1; d < 256; d <<= 1) {
            int x = tot[t];
            int y = (t >= d) ? tot[t - d] : 0;
            __syncthreads();
            tot[t] = x + y;
            __syncthreads();
        }
        int excl = tot[t] - tsum;
        if (base + 0 < N_SEG) offs[base + 0] = excl;
        if (base + 1 < N_SEG) offs[base + 1] = excl + v0;
        if (base + 2 < N_SEG) offs[base + 2] = excl + v0 + v1;
        if (base + 3 < N_SEG) offs[base + 3] = excl + v0 + v1 + v2;
        if (t == 255) partials[bid] = tot[255];
    } else if (bid < NCHUNK + RP_B) {
        int idx = (bid - NCHUNK) * 256 + t;
        int k = idx >> 7, n = idx & 127;
        float val;
        if (k < N_REL * C) val = W1[(size_t)k * C + n];
        else               val = root1[(size_t)(k - N_REL * C) * C + n];
        Bp1[frag_index(k, n)] = __float2bfloat16(val);
    } else if (bid < NCHUNK + RP_B + RPT_B) {
        // ---- tiled repack2: out(k0+ty, n0+tx) = sum_m W2cat[k0+ty][m] * linW[m][n0+tx]
        __shared__ float Wt[16][128];    // 8 KB
        __shared__ float Lt[128][16];    // 8 KB
        int tileid = bid - NCHUNK - RP_B;
        int kt = tileid >> 3;            // 0..71  (k0 = kt*16; 1024 boundary not straddled)
        int n0 = (tileid & 7) * 16;
        int k0 = kt * 16;
        const float* baseW = (k0 < N_REL * C) ? (W2 + (size_t)k0 * C)
                                              : (root2 + (size_t)(k0 - N_REL * C) * C);
#pragma unroll
        for (int r = 0; r < 8; r++) {            // 2048 elems, coalesced
            int idx = t + r * 256;
            Wt[idx >> 7][idx & 127] = baseW[idx];
        }
#pragma unroll
        for (int r = 0; r < 8; r++) {            // 2048 elems: m = idx>>4, n = idx&15
            int idx = t + r * 256;
            Lt[idx >> 4][idx & 15] = linW[(size_t)(idx >> 4) * C + n0 + (idx & 15)];
        }
        __syncthreads();
        int ty = t >> 4, tx = t & 15;
        float acc = 0.f;
#pragma unroll 8
        for (int m = 0; m < 128; m++)
            acc += Wt[ty][m] * Lt[m][tx];
        Bp2[frag_index(k0 + ty, n0 + tx)] = __float2bfloat16(acc);
    } else {
        if (t < 128) {
            float acc = linb[t];
            for (int m = 0; m < C; m++)
                acc += b2[m] * linW[(size_t)m * C + t];
            b2p[t] = acc;
        }
    }
}

// ---------------------------------------------------------------- fillB: offs finalize + edge fill
__global__ void fillB_kernel(const int* __restrict__ src, const int* __restrict__ dst,
                             const int* __restrict__ et,
                             const int* __restrict__ offs_raw,   // scanA output
                             const int* __restrict__ partials,
                             int* __restrict__ offs_final,
                             int* __restrict__ ticket,           // zeroed [N_SEG]
                             int* __restrict__ srcs_out) {
    __shared__ int s[512];
    int t = threadIdx.x;
    int bid = blockIdx.x;
    s[t] = (t < NCHUNK) ? partials[t] : 0;
    __syncthreads();
    for (int d = 1; d < 512; d <<= 1) {
        int x = s[t];
        int y = (t >= d) ? s[t - d] : 0;
        __syncthreads();
        s[t] = x + y;          // inclusive scan
        __syncthreads();
    }
    if (bid < NCHUNK) {
        int add = (bid == 0) ? 0 : s[bid - 1];
        int base = bid * 1024 + t * 2;
#pragma unroll
        for (int j = 0; j < 2; j++) {
            int idx = base + j;
            if (idx < N_SEG) offs_final[idx] = offs_raw[idx] + add;
        }
        if (bid == 0 && t == 0) offs_final[N_SEG] = N_EDGES;
    } else {
        int e = (bid - NCHUNK) * 512 + t;
        if (e < N_EDGES) {
            int seg = dst[e] * N_REL + et[e];
            int chunk = seg >> 10;
            int base = offs_raw[seg] + ((chunk == 0) ? 0 : s[chunk - 1]);
            int pos = base + atomicAdd(&ticket[seg], 1);
            srcs_out[pos] = src[e];
        }
    }
}

// ---------------------------------------------------------------- fused layer
// Block: 16 nodes, 512 threads (8 waves). Wave w owns local segments
// [16w, 16w+16) (contiguous CSR edge range). EXPLICIT 2-stage pipeline:
// batch k+1's 16 srcs+gather loads issue in a straight-line block BEFORE the
// branchy fold of batch k, so the compiler cannot sink/serialize them
// (R9/R10 showed it does exactly that when loads and fold share a BB).
template <int RELU, int OUT_F32, int COPY_CSR>
__global__ __launch_bounds__(512, 6) void fused_layer(
        const unsigned int* __restrict__ featu,  // [N][64] bf16 pairs
        const int*   __restrict__ offs,          // [N_SEG+1]
        const int*   __restrict__ srcs,          // [N_EDGES]
        const short8* __restrict__ Bp,           // fragment-packed bf16 weights
        const float* __restrict__ bias,          // [128] fp32
        void* __restrict__ outp,                 // [N][128] fp32 or bf16
        int* __restrict__ offs2, int* __restrict__ srcs2)   // CSR copy dst
{
    __shared__ __align__(16) unsigned int At[16 * (A_STRIDE / 2)];  // bf16 pairs
    __shared__ int offsL[129];
    const int tid  = threadIdx.x;
    const int lane = tid & 63;
    const int w    = tid >> 6;          // 0..7
    const int v0   = blockIdx.x * 16;

    if (tid < 129) offsL[tid] = offs[v0 * 8 + tid];
    if (tid < 64)  At[(tid >> 2) * (A_STRIDE / 2) + 576 + (tid & 3)] = 0u;  // pad pairs

    // relocate CSR slice (overlapped with gather latency)
    if (COPY_CSR) {
        for (int i = blockIdx.x * 512 + tid; i < MV_N; i += NBLK * 512) {
            if (i < N_SEG + 1) offs2[i] = offs[i];
            else               srcs2[i - (N_SEG + 1)] = srcs[i - (N_SEG + 1)];
        }
    }

    // self rows -> k range [1024..1151]
    for (int q = tid; q < 16 * 64; q += 512) {
        int node = q >> 6, pch = q & 63;
        At[node * (A_STRIDE / 2) + 512 + pch] = featu[(size_t)(v0 + node) * 64 + pch];
    }
    __syncthreads();

    // ---- aggregation over wave-owned contiguous edge range (16 segments)
    {
        const int segLo = w * 16;
        const int segHi = segLo + 16;
        int curSeg = segLo;
        int segEnd = offsL[curSeg + 1];
        int i      = offsL[segLo];
        const int eend = offsL[segHi];
        float a0 = 0.f, a1 = 0.f;

        unsigned int vals[16];
        bool have = (i + 16 <= eend);
        if (have) {
            const int ib = __builtin_amdgcn_readfirstlane(i);
            int sv[16];
#pragma unroll
            for (int j = 0; j < 16; j++) sv[j] = srcs[ib + j];
#pragma unroll
            for (int j = 0; j < 16; j++) vals[j] = featu[(size_t)sv[j] * 64 + lane];
        }
        while (have) {
            const int inext = i + 16;
            const bool havenext = (inext + 16 <= eend);
            unsigned int vals2[16];
            if (havenext) {                       // prefetch batch k+1 (straight-line)
                const int ib2 = __builtin_amdgcn_readfirstlane(inext);
                int sv2[16];
#pragma unroll
                for (int j = 0; j < 16; j++) sv2[j] = srcs[ib2 + j];
#pragma unroll
                for (int j = 0; j < 16; j++) vals2[j] = featu[(size_t)sv2[j] * 64 + lane];
            }
            // fold batch k
#pragma unroll
            for (int j = 0; j < 16; j++) {
                while (i + j == segEnd) {         // flush finished segment(s)
                    int b = offsL[curSeg];
                    float inv = (segEnd > b) ? 1.0f / (float)(segEnd - b) : 0.0f;
                    union { bf162 h; unsigned int u; } cv;
                    cv.h = bf162(__float2bfloat16(a0 * inv), __float2bfloat16(a1 * inv));
                    At[(curSeg >> 3) * (A_STRIDE / 2) + (curSeg & 7) * 64 + lane] = cv.u;
                    a0 = 0.f; a1 = 0.f;
                    curSeg++;
                    segEnd = offsL[curSeg + 1];
                }
                union { bf162 h; unsigned int u; } uv; uv.u = vals[j];
                a0 += __low2float(uv.h);
                a1 += __high2float(uv.h);
            }
            i = inext;
            have = havenext;
            if (havenext) {
#pragma unroll
                for (int j = 0; j < 16; j++) vals[j] = vals2[j];
            }
        }
        // predicated tail batch (m < 16, wave-uniform)
        {
            int m = eend - i;
            const int ib = __builtin_amdgcn_readfirstlane(i);
            int sv[16];
#pragma unroll
            for (int j = 0; j < 16; j++) if (j < m) sv[j] = srcs[ib + j];
            unsigned int tvals[16];
#pragma unroll
            for (int j = 0; j < 16; j++) if (j < m) tvals[j] = featu[(size_t)sv[j] * 64 + lane];
#pragma unroll
            for (int j = 0; j < 16; j++) {
                if (j < m) {
                    while (i + j == segEnd) {
                        int b = offsL[curSeg];
                        float inv = (segEnd > b) ? 1.0f / (float)(segEnd - b) : 0.0f;
                        union { bf162 h; unsigned int u; } cv;
                        cv.h = bf162(__float2bfloat16(a0 * inv), __float2bfloat16(a1 * inv));
                        At[(curSeg >> 3) * (A_STRIDE / 2) + (curSeg & 7) * 64 + lane] = cv.u;
                        a0 = 0.f; a1 = 0.f;
                        curSeg++;
                        segEnd = offsL[curSeg + 1];
                    }
                    union { bf162 h; unsigned int u; } uv; uv.u = tvals[j];
                    a0 += __low2float(uv.h);
                    a1 += __high2float(uv.h);
                }
            }
        }
        // trailing flushes (last non-empty segment + empty tails)
        while (curSeg < segHi) {
            int b = offsL[curSeg], e2 = offsL[curSeg + 1];
            float inv = (e2 > b) ? 1.0f / (float)(e2 - b) : 0.0f;
            union { bf162 h; unsigned int u; } cv;
            cv.h = bf162(__float2bfloat16(a0 * inv), __float2bfloat16(a1 * inv));
            At[(curSeg >> 3) * (A_STRIDE / 2) + (curSeg & 7) * 64 + lane] = cv.u;
            a0 = 0.f; a1 = 0.f;
            curSeg++;
        }
    }
    __syncthreads();

    // ---- MFMA GEMM: wave w computes N-tile w (cols 16w..16w+15)
    const int quad = lane >> 4, n15 = lane & 15;
    f32x4 acc = {0.f, 0.f, 0.f, 0.f};
    const short* Ash = (const short*)At;

    short8 b0 = Bp[(size_t)(w * KC_CNT) * 64 + lane];
#pragma unroll 4
    for (int kc = 0; kc < KC_CNT; kc++) {
        short8 cb0 = b0;
        if (kc + 1 < KC_CNT)
            b0 = Bp[(size_t)(w * KC_CNT + kc + 1) * 64 + lane];
        short8 a = *reinterpret_cast<const short8*>(Ash + n15 * A_STRIDE + kc * 32 + quad * 8);
        acc = __builtin_amdgcn_mfma_f32_16x16x32_bf16(a, cb0, acc, 0, 0, 0);
    }

    // epilogue: D[m = quad*4 + r][col = w*16 + n15]
    {
        int col = w * 16 + n15;
        float bv = bias[col];
#pragma unroll
        for (int r = 0; r < 4; r++) {
            int m = quad * 4 + r;
            float v = acc[r] + bv;
            if (RELU) v = fmaxf(v, 0.f);
            if (OUT_F32) ((float*)outp)[(size_t)(v0 + m) * C + col] = v;
            else         ((bf16*)outp)[(size_t)(v0 + m) * C + col] = __float2bfloat16(v);
        }
    }
}

// ---------------------------------------------------------------- launch
// fp32 I/O. ZERO d_ws usage. Provenance:
//   d_out lo   : CSR scratch (cnt/ticket/offs_raw/partials/srcs/offs_final)
//   d_out hi   : x as bf16 (12.8 MB @ +10 MB, 256B-ALIGNED)   [dead after layer 1]
//   x buffer lo: h1 bf16 (12.8 MB)                            [x fp32 dead after cvt]
//   x buffer hi: packed weights Bp1/Bp2/b2p (@ +13.0 MB)      [written in scanA]
//   ei buffer  : final CSR (offs2+srcs2), copied BY layer 1   [ei dead after fillB]
//   d_out      : final fp32 output (layer 2 writes directly)
extern "C" void kernel_launch(void* const* d_in, const int* in_sizes, int n_in,
                              void* d_out, int out_size, void* d_ws, size_t ws_size,
                              hipStream_t stream) {
    const float* x     = (const float*)d_in[0];
    const int*   ei    = (const int*)d_in[1];
    const int*   et    = (const int*)d_in[2];
    const float* W1    = (const float*)d_in[3];
    const float* root1 = (const float*)d_in[4];
    const float* b1    = (const float*)d_in[5];
    const float* W2    = (const float*)d_in[6];
    const float* root2 = (const float*)d_in[7];
    const float* b2    = (const float*)d_in[8];
    const float* linW  = (const float*)d_in[9];
    const float* linb  = (const float*)d_in[10];
    const int* src = ei;
    const int* dst = ei + N_EDGES;

    // ---- d_out scratch
    char* ob = (char*)d_out;
    int* cnt_i    = (int*)(ob + 0);          // 1,600,000 B
    int* ticket   = (int*)(ob + 1600000);    // 1,600,000 B (memset covers both)
    int* offs_t   = (int*)(ob + 3200000);    // 1,600,004 B (raw chunk-local scans)
    int* partials = (int*)(ob + 4800256);    // 1,564 B
    int* offs_f   = (int*)(ob + 4803072);    // 1,600,004 B (final offs)
    int* srcs_t   = (int*)(ob + 6403328);    // 4,000,000 B -> ends 10,403,328
    unsigned int* xb16 = (unsigned int*)(ob + 10485760); // 256B-aligned; ends 23,285,760 < 25.6 MB

    // ---- ei buffer: final CSR (written by layer 1's copy slice)
    char* eb = (char*)d_in[1];
    int* offs2 = (int*)(eb + 0);
    int* srcs2 = (int*)(eb + 1600256);       // ends 5,600,256 < 8 MB

    // ---- x buffer: h1 low, weights high
    char* xbuf = (char*)d_in[0];
    unsigned int* h1 = (unsigned int*)xbuf;          // 12.8 MB
    bf16*  Bp1 = (bf16*)(xbuf + 13000192);           // 16B-aligned, 294,912 B
    bf16*  Bp2 = (bf16*)(xbuf + 13295360);           // 294,912 B
    float* b2p = (float*)(xbuf + 13590528);          // 512 B -> ends < 25.6 MB

    float* out = (float*)d_out;

    hipMemsetAsync(cnt_i, 0, 3200000, stream);   // cnt + ticket
    prep_kernel<<<CVT_BLOCKS + CNT_BLOCKS, 256, 0, stream>>>(
        (const float2*)x, xb16, dst, et, cnt_i);
    scanA_kernel<<<NCHUNK + RP_B + RPT_B + 1, 256, 0, stream>>>(
        cnt_i, offs_t, partials, W1, root1, W2, root2, linW, b2, linb,
        Bp1, Bp2, b2p);
    fillB_kernel<<<NCHUNK + FE_BLK, 512, 0, stream>>>(
        src, dst, et, offs_t, partials, offs_f, ticket, srcs_t);

    fused_layer<1, 0, 1><<<NBLK, 512, 0, stream>>>(
        xb16, offs_f, srcs_t, (const short8*)Bp1, b1, (void*)h1, offs2, srcs2);
    fused_layer<0, 1, 0><<<NBLK, 512, 0, stream>>>(
        h1, offs2, srcs2, (const short8*)Bp2, b2p, (void*)out, nullptr, nullptr);

    (void)in_sizes; (void)n_in; (void)out_size; (void)d_ws; (void)ws_size;
}